// Round 2
// baseline (517.263 us; speedup 1.0000x reference)
//
#include <hip/hip_runtime.h>

typedef _Float16 half8_t __attribute__((ext_vector_type(8)));
typedef float f32x4 __attribute__((ext_vector_type(4)));

#define B_ 128
#define N_ 4096
#define H_ 128
#define P_ 128
#define CCH 8                        // chunks per batch row -> 1024 blocks = 4/CU exactly
#define ROWS_PER_CHUNK (N_ / CCH)    // 512
#define TILES (ROWS_PER_CHUNK / 64)  // 8 iterations of 64 rows (16/wave)

// workspace layout
#define OFF_CNT    1024       // INT index into (int*)ws: 128 per-batch counters (memset 0 each launch)
#define OFF_LOGITS 24832      // float index: B*N logits
#define OFF_PART   549120     // float index: B*CCH*132: per-(b,chunk) m,l,o[128],pad2

// ---------- single fused kernel ----------
// R7: k0 and k2 are gone.
//  - Scale-free B-pack: relu(sv*x)=sv*relu(x) (sv>0), so Bl holds RAW Wv in
//    fragment order; sv folds into was[] (wa*sa*sv) and the C-init becomes
//    (q.Wq*sq + bq + bv)/sv. Each block packs from L2-hot Wv itself, and the
//    three weight-norm square-sums ride along on loads the prologue already
//    does (Wv via pack, Wq via qproj, Wa direct) + one shuffle/LDS reduction.
//  - Last-block-per-batch finalize (rocPRIM pattern): producer blocks
//    __syncthreads (drain stores to L2) -> __threadfence (wbl2 release) ->
//    atomicAdd(cnt[b]); the 8th arrival fences (buffer_inv acquire) and does
//    the k2 work for batch b, overlapped with other blocks' tails.
__global__ __launch_bounds__(256) void k_fused(
    const float* __restrict__ v, const float* __restrict__ mask,
    const float* __restrict__ ba,
    const float* __restrict__ q, const float* __restrict__ Wq,
    const float* __restrict__ bq, const float* __restrict__ bv,
    const float* __restrict__ Wv, const float* __restrict__ gv,
    const float* __restrict__ gq, const float* __restrict__ Wa,
    const float* __restrict__ ga,
    float* __restrict__ ws, float* __restrict__ out)
{
    const int c = blockIdx.x;   // chunk
    const int b = blockIdx.y;   // batch
    const int tid = threadIdx.x;
    const int lane = tid & 63;
    const int w = tid >> 6;     // wave id 0..3

    __shared__ __align__(16) _Float16 Bl[16384];   // 32 KB packed B-frags (raw Wv)
    __shared__ float qpcs[P_];
    __shared__ float was[P_];
    __shared__ float smask[ROWS_PER_CHUNK];        // 2 KB chunk mask
    __shared__ float obuf[4][P_];                  // per-wave o partials
    __shared__ float mbuf[4], lbuf[4];
    __shared__ float red3[4][3];
    __shared__ int s_win;

    float sv2 = 0.f, sq2 = 0.f, sa2 = 0.f;

    // ---- pack raw Wv -> Bl in MFMA B-fragment order; fuse |Wv|^2 partial.
    // Bl[s]: s = ((kk*8+pt)*64 + L)*8 + j  <-  Wv[p][h] with
    // p = pt*16 + (L&15), h = kk*32 + (L>>4)*8 + j
#pragma unroll
    for (int g = 0; g < 8; ++g) {
        const int idx = w * 8 + g;          // 0..31 = (kk,pt), wave-uniform
        const int kk = idx >> 3, pt = idx & 7;
        const int p = pt * 16 + (lane & 15);
        const int h = kk * 32 + (lane >> 4) * 8;
        const float4* src = (const float4*)(Wv + (size_t)p * H_ + h);
        float4 f0 = src[0], f1 = src[1];
        sv2 += f0.x * f0.x + f0.y * f0.y + f0.z * f0.z + f0.w * f0.w
             + f1.x * f1.x + f1.y * f1.y + f1.z * f1.z + f1.w * f1.w;
        half8_t a;
        a[0] = (_Float16)f0.x; a[1] = (_Float16)f0.y;
        a[2] = (_Float16)f0.z; a[3] = (_Float16)f0.w;
        a[4] = (_Float16)f1.x; a[5] = (_Float16)f1.y;
        a[6] = (_Float16)f1.z; a[7] = (_Float16)f1.w;
        *(half8_t*)&Bl[(((kk * 8 + pt) * 64) + lane) * 8] = a;
    }

    // ---- raw q_proj dot (scale applied after reduction); fuse |Wq|^2 partial
    {
        const int p  = tid >> 1;
        const int hh = tid & 1;
        const float4* qr = (const float4*)(q + (size_t)b * H_) + hh * 16;
        const float4* wr = (const float4*)(Wq + (size_t)p * H_) + hh * 16;
        float dot = 0.f;
#pragma unroll
        for (int i = 0; i < 16; ++i) {
            float4 a = qr[i], c4 = wr[i];
            dot += a.x * c4.x + a.y * c4.y + a.z * c4.z + a.w * c4.w;
            sq2 += c4.x * c4.x + c4.y * c4.y + c4.z * c4.z + c4.w * c4.w;
        }
        dot += __shfl_xor(dot, 1, 64);
        if (hh == 0) qpcs[p] = dot;        // raw; fixed up below
    }

    float wa_z = 0.f;
    if (tid < P_) { wa_z = Wa[tid]; sa2 = wa_z * wa_z; }

#pragma unroll
    for (int i = 0; i < ROWS_PER_CHUNK / 256; ++i)
        smask[tid + i * 256] = mask[(size_t)b * N_ + c * ROWS_PER_CHUNK + tid + i * 256];

    // ---- block-reduce the three square-sums
#pragma unroll
    for (int m = 1; m <= 32; m <<= 1) {
        sv2 += __shfl_xor(sv2, m, 64);
        sq2 += __shfl_xor(sq2, m, 64);
        sa2 += __shfl_xor(sa2, m, 64);
    }
    if (lane == 0) { red3[w][0] = sv2; red3[w][1] = sq2; red3[w][2] = sa2; }
    __syncthreads();
    const float nv = red3[0][0] + red3[1][0] + red3[2][0] + red3[3][0];
    const float nq = red3[0][1] + red3[1][1] + red3[2][1] + red3[3][1];
    const float na = red3[0][2] + red3[1][2] + red3[2][2] + red3[3][2];
    const float rnv = sqrtf(nv);
    const float sv = gv[0] / rnv;
    const float inv_sv = rnv / gv[0];
    const float sq = gq[0] / sqrtf(nq);
    const float sa = ga[0] / sqrtf(na);

    if (tid < P_) {
        qpcs[tid] = (qpcs[tid] * sq + bq[tid] + bv[tid]) * inv_sv;
        was[tid]  = wa_z * (sa * sv);
    }
    const float ba0 = ba[0];
    __syncthreads();

    const int rloc = lane & 15;        // v-row owned by this lane (A-frag m)
    const int grp  = lane >> 4;        // 16-lane group id 0..3
    const int colb = grp * 8;          // col sub-block within each 32-col slice

    float m_w = -1e30f, l_w = 0.f;
    float o32[32];
#pragma unroll
    for (int j = 0; j < 32; ++j) o32[j] = 0.f;

    for (int it = 0; it < TILES; ++it) {
        const int r0 = it * 64 + w * 16;                 // row offset in chunk
        const int n0w = c * ROWS_PER_CHUNK + r0;         // global row

        // ---- load 16x128 tile -> f16 A-frags (sole HBM touch of v)
        const float* vrow = v + ((size_t)b * N_ + n0w + rloc) * H_;
        half8_t af[4];
#pragma unroll
        for (int kk = 0; kk < 4; ++kk) {
            const float4* p4 = (const float4*)(vrow + kk * 32 + colb);
            float4 f0 = p4[0], f1 = p4[1];
            half8_t a;
            a[0] = (_Float16)f0.x; a[1] = (_Float16)f0.y;
            a[2] = (_Float16)f0.z; a[3] = (_Float16)f0.w;
            a[4] = (_Float16)f1.x; a[5] = (_Float16)f1.y;
            a[6] = (_Float16)f1.z; a[7] = (_Float16)f1.w;
            af[kk] = a;
        }

        // ---- v_proj via MFMA + relu·wa partial logits
        float lp[4];
        lp[0] = lp[1] = lp[2] = lp[3] = 0.f;
#pragma unroll
        for (int pt = 0; pt < 8; ++pt) {
            const int p = pt * 16 + rloc;
            const float qv = qpcs[p];
            f32x4 acc = {qv, qv, qv, qv};      // C init = (q_proj+bq+bv)/sv
#pragma unroll
            for (int kk = 0; kk < 4; ++kk) {
                half8_t bf = *(const half8_t*)&Bl[(((kk * 8 + pt) * 64) + lane) * 8];
                acc = __builtin_amdgcn_mfma_f32_16x16x32_f16(af[kk], bf, acc, 0, 0, 0);
            }
            const float wv = was[p];           // wa*sa*sv: relu(sv x)=sv relu(x)
#pragma unroll
            for (int r = 0; r < 4; ++r)
                lp[r] += fmaxf(acc[r], 0.f) * wv;
        }
        // reduce over the 16 p-cols (lanes differing in bits 0-3)
#pragma unroll
        for (int m = 1; m <= 8; m <<= 1) {
#pragma unroll
            for (int r = 0; r < 4; ++r) lp[r] += __shfl_xor(lp[r], m, 64);
        }
        // lp[r] is now the logit of row (grp*4 + r); add bias + mask (LDS)
#pragma unroll
        for (int r = 0; r < 4; ++r) {
            const float mk = smask[r0 + grp * 4 + r];
            lp[r] += ba0 + (1.0f - mk) * (-10000.0f);
        }

        // transpose: lg_me = logit of row rloc (the row this lane HOLDS)
        const int srcl = (rloc >> 2) << 4;
        float t0 = __shfl(lp[0], srcl, 64);
        float t1 = __shfl(lp[1], srcl, 64);
        float t2 = __shfl(lp[2], srcl, 64);
        float t3 = __shfl(lp[3], srcl, 64);
        float a01 = (rloc & 1) ? t1 : t0;
        float a23 = (rloc & 1) ? t3 : t2;
        float lg_me = (rloc & 2) ? a23 : a01;

        // store logits (lanes 0..15 cover rows n0w..n0w+15, coalesced)
        if (lane < 16) ws[OFF_LOGITS + (size_t)b * N_ + n0w + lane] = lg_me;

        // wave max over its 16 rows
        float mt = fmaxf(fmaxf(lp[0], lp[1]), fmaxf(lp[2], lp[3]));
        mt = fmaxf(mt, __shfl_xor(mt, 16, 64));
        mt = fmaxf(mt, __shfl_xor(mt, 32, 64));

        // wave-private online softmax update
        const float mn = fmaxf(m_w, mt);
        const float alpha = __expf(m_w - mn);
        const float wme = __expf(lg_me - mn);
        float s = wme;
#pragma unroll
        for (int m = 1; m <= 8; m <<= 1) s += __shfl_xor(s, m, 64);
        l_w = l_w * alpha + s;
        m_w = mn;

        if (alpha != 1.0f) {
#pragma unroll
            for (int j = 0; j < 32; ++j) o32[j] *= alpha;
        }
        // o-update from the registers we already hold (f16 -> f32 cvt)
#pragma unroll
        for (int kk = 0; kk < 4; ++kk) {
#pragma unroll
            for (int j = 0; j < 8; ++j)
                o32[kk * 8 + j] += wme * (float)af[kk][j];
        }
    }

    // ---- intra-wave o reduction over the 16 rows (lanes, bits 0-3)
#pragma unroll
    for (int m = 1; m <= 8; m <<= 1) {
#pragma unroll
        for (int j = 0; j < 32; ++j) o32[j] += __shfl_xor(o32[j], m, 64);
    }
    {
        const int j0 = rloc * 2;
#pragma unroll
        for (int u = 0; u < 2; ++u) {
            const int j = j0 + u;
            obuf[w][(j >> 3) * 32 + colb + (j & 7)] = o32[j];
        }
        if (lane == 0) { mbuf[w] = m_w; lbuf[w] = l_w; }
    }
    __syncthreads();

    // ---- merge 4 wave partials -> chunk partial
    {
        float* part = ws + OFF_PART + ((size_t)b * CCH + c) * 132;
        if (tid < P_) {
            const float mb = fmaxf(fmaxf(mbuf[0], mbuf[1]), fmaxf(mbuf[2], mbuf[3]));
            float lb = 0.f, oh = 0.f;
#pragma unroll
            for (int ww = 0; ww < 4; ++ww) {
                const float e = __expf(mbuf[ww] - mb);
                lb += e * lbuf[ww];
                oh += e * obuf[ww][tid];
            }
            part[2 + tid] = oh;
            if (tid == 0) { part[0] = mb; part[1] = lb; }
        }
    }

    // ---- last-block-per-batch finalize (release/acquire via device atomics)
    __syncthreads();                    // all stores drained to this XCD's L2
    if (tid == 0) {
        __threadfence();                // wbl2: publish to coherent point
        int old = atomicAdd((int*)ws + OFF_CNT + b, 1);
        s_win = (old == CCH - 1) ? 1 : 0;
    }
    __syncthreads();
    if (!s_win) return;
    __threadfence();                    // buffer_inv: drop stale L1/L2 lines

    const float* part = ws + OFF_PART + (size_t)b * CCH * 132;
    float m = -1e30f;
#pragma unroll
    for (int cc = 0; cc < CCH; ++cc) m = fmaxf(m, part[cc * 132]);
    float l = 0.f;
#pragma unroll
    for (int cc = 0; cc < CCH; ++cc)
        l += __expf(part[cc * 132] - m) * part[cc * 132 + 1];
    const float il = 1.0f / l;

    if (tid < P_) {
        float a = 0.f;
#pragma unroll
        for (int cc = 0; cc < CCH; ++cc)
            a += __expf(part[cc * 132] - m) * part[cc * 132 + 2 + tid];
        out[(size_t)b * H_ + tid] = a * il;
    }

    const float4* lg4 = (const float4*)(ws + OFF_LOGITS + (size_t)b * N_);
    float4* w4 = (float4*)(out + B_ * H_ + (size_t)b * N_);
#pragma unroll
    for (int u = 0; u < 4; ++u) {
        const int i = tid + u * 256;    // 1024 float4 = 4096 w values
        float4 g = lg4[i];
        float4 r;
        r.x = __expf(g.x - m) * il;
        r.y = __expf(g.y - m) * il;
        r.z = __expf(g.z - m) * il;
        r.w = __expf(g.w - m) * il;
        w4[i] = r;
    }
}

extern "C" void kernel_launch(void* const* d_in, const int* in_sizes, int n_in,
                              void* d_out, int out_size, void* d_ws, size_t ws_size,
                              hipStream_t stream) {
    const float* v    = (const float*)d_in[0];
    const float* q    = (const float*)d_in[1];
    const float* mask = (const float*)d_in[2];
    const float* Wv   = (const float*)d_in[3];
    const float* bv   = (const float*)d_in[4];
    const float* gv   = (const float*)d_in[5];
    const float* Wq   = (const float*)d_in[6];
    const float* bq   = (const float*)d_in[7];
    const float* gq   = (const float*)d_in[8];
    const float* Wa   = (const float*)d_in[9];
    const float* ba   = (const float*)d_in[10];
    const float* ga   = (const float*)d_in[11];
    float* out = (float*)d_out;
    float* ws  = (float*)d_ws;

    // zero the 128 per-batch arrival counters (ws is poisoned every iter)
    hipMemsetAsync((char*)d_ws + OFF_CNT * sizeof(int), 0, B_ * sizeof(int), stream);
    k_fused<<<dim3(CCH, B_), 256, 0, stream>>>(v, mask, ba, q, Wq, bq, bv,
                                               Wv, gv, gq, Wa, ga, ws, out);
}

// Round 3
// 405.764 us; speedup vs baseline: 1.2748x; 1.2748x over previous
//
#include <hip/hip_runtime.h>

typedef _Float16 half8_t __attribute__((ext_vector_type(8)));
typedef float f32x4 __attribute__((ext_vector_type(4)));

#define B_ 128
#define N_ 4096
#define H_ 128
#define P_ 128
#define CCH 8                        // chunks per batch row -> 1024 blocks = 4/CU exactly
#define ROWS_PER_CHUNK (N_ / CCH)    // 512
#define TILES (ROWS_PER_CHUNK / 64)  // 8 iterations of 64 rows (16/wave)

// workspace layout (float offsets)
#define OFF_LOGITS 24832      // B*N floats
#define OFF_PART   549120     // B*CCH*132 floats: per-(b,chunk) m,l,o[128],pad2

// ---------- K1: fused prep + one pass over v ----------
// R8: R2's inline prep (scale-free B-pack, fused weight norms, inline qproj)
// is KEPT; R2's last-block finalize is REMOVED — its per-block
// __threadfence() (buffer_wbl2 + buffer_inv = full XCD-L2 flush/invalidate)
// thrashed the L2 under all co-resident v-streams (hbm 6.3 TB/s -> 0.56,
// kernel 89 -> 200+ us). Cross-block reduction goes back to a 2nd kernel.
//  - Scale-free B-pack: relu(sv*x)=sv*relu(x) (sv>0), so Bl holds RAW Wv in
//    fragment order; sv folds into was[] (wa*sa*sv) and the C-init becomes
//    (q.Wq*sq + bq + bv)/sv. Weight-norm square-sums ride along on loads the
//    prologue already does (Wv via pack, Wq via qproj, Wa direct).
__global__ __launch_bounds__(256) void k1_main(
    const float* __restrict__ v, const float* __restrict__ mask,
    const float* __restrict__ ba,
    const float* __restrict__ q, const float* __restrict__ Wq,
    const float* __restrict__ bq, const float* __restrict__ bv,
    const float* __restrict__ Wv, const float* __restrict__ gv,
    const float* __restrict__ gq, const float* __restrict__ Wa,
    const float* __restrict__ ga,
    float* __restrict__ ws)
{
    const int c = blockIdx.x;   // chunk
    const int b = blockIdx.y;   // batch
    const int tid = threadIdx.x;
    const int lane = tid & 63;
    const int w = tid >> 6;     // wave id 0..3

    __shared__ __align__(16) _Float16 Bl[16384];   // 32 KB packed B-frags (raw Wv)
    __shared__ float qpcs[P_];
    __shared__ float was[P_];
    __shared__ float smask[ROWS_PER_CHUNK];        // 2 KB chunk mask
    __shared__ float obuf[4][P_];                  // per-wave o partials
    __shared__ float mbuf[4], lbuf[4];
    __shared__ float red3[4][3];

    float sv2 = 0.f, sq2 = 0.f, sa2 = 0.f;

    // ---- pack raw Wv -> Bl in MFMA B-fragment order; fuse |Wv|^2 partial.
    // Bl[s]: s = ((kk*8+pt)*64 + L)*8 + j  <-  Wv[p][h] with
    // p = pt*16 + (L&15), h = kk*32 + (L>>4)*8 + j
#pragma unroll
    for (int g = 0; g < 8; ++g) {
        const int idx = w * 8 + g;          // 0..31 = (kk,pt), wave-uniform
        const int kk = idx >> 3, pt = idx & 7;
        const int p = pt * 16 + (lane & 15);
        const int h = kk * 32 + (lane >> 4) * 8;
        const float4* src = (const float4*)(Wv + (size_t)p * H_ + h);
        float4 f0 = src[0], f1 = src[1];
        sv2 += f0.x * f0.x + f0.y * f0.y + f0.z * f0.z + f0.w * f0.w
             + f1.x * f1.x + f1.y * f1.y + f1.z * f1.z + f1.w * f1.w;
        half8_t a;
        a[0] = (_Float16)f0.x; a[1] = (_Float16)f0.y;
        a[2] = (_Float16)f0.z; a[3] = (_Float16)f0.w;
        a[4] = (_Float16)f1.x; a[5] = (_Float16)f1.y;
        a[6] = (_Float16)f1.z; a[7] = (_Float16)f1.w;
        *(half8_t*)&Bl[(((kk * 8 + pt) * 64) + lane) * 8] = a;
    }

    // ---- raw q_proj dot (scale applied after reduction); fuse |Wq|^2 partial
    {
        const int p  = tid >> 1;
        const int hh = tid & 1;
        const float4* qr = (const float4*)(q + (size_t)b * H_) + hh * 16;
        const float4* wr = (const float4*)(Wq + (size_t)p * H_) + hh * 16;
        float dot = 0.f;
#pragma unroll
        for (int i = 0; i < 16; ++i) {
            float4 a = qr[i], c4 = wr[i];
            dot += a.x * c4.x + a.y * c4.y + a.z * c4.z + a.w * c4.w;
            sq2 += c4.x * c4.x + c4.y * c4.y + c4.z * c4.z + c4.w * c4.w;
        }
        dot += __shfl_xor(dot, 1, 64);
        if (hh == 0) qpcs[p] = dot;        // raw; fixed up below
    }

    float wa_z = 0.f;
    if (tid < P_) { wa_z = Wa[tid]; sa2 = wa_z * wa_z; }

#pragma unroll
    for (int i = 0; i < ROWS_PER_CHUNK / 256; ++i)
        smask[tid + i * 256] = mask[(size_t)b * N_ + c * ROWS_PER_CHUNK + tid + i * 256];

    // ---- block-reduce the three square-sums
#pragma unroll
    for (int m = 1; m <= 32; m <<= 1) {
        sv2 += __shfl_xor(sv2, m, 64);
        sq2 += __shfl_xor(sq2, m, 64);
        sa2 += __shfl_xor(sa2, m, 64);
    }
    if (lane == 0) { red3[w][0] = sv2; red3[w][1] = sq2; red3[w][2] = sa2; }
    __syncthreads();
    const float nv = red3[0][0] + red3[1][0] + red3[2][0] + red3[3][0];
    const float nq = red3[0][1] + red3[1][1] + red3[2][1] + red3[3][1];
    const float na = red3[0][2] + red3[1][2] + red3[2][2] + red3[3][2];
    const float rnv = sqrtf(nv);
    const float sv = gv[0] / rnv;
    const float inv_sv = rnv / gv[0];
    const float sq = gq[0] / sqrtf(nq);
    const float sa = ga[0] / sqrtf(na);

    if (tid < P_) {
        qpcs[tid] = (qpcs[tid] * sq + bq[tid] + bv[tid]) * inv_sv;
        was[tid]  = wa_z * (sa * sv);
    }
    const float ba0 = ba[0];
    __syncthreads();

    const int rloc = lane & 15;        // v-row owned by this lane (A-frag m)
    const int grp  = lane >> 4;        // 16-lane group id 0..3
    const int colb = grp * 8;          // col sub-block within each 32-col slice

    float m_w = -1e30f, l_w = 0.f;
    float o32[32];
#pragma unroll
    for (int j = 0; j < 32; ++j) o32[j] = 0.f;

    for (int it = 0; it < TILES; ++it) {
        const int r0 = it * 64 + w * 16;                 // row offset in chunk
        const int n0w = c * ROWS_PER_CHUNK + r0;         // global row

        // ---- load 16x128 tile -> f16 A-frags (sole HBM touch of v)
        const float* vrow = v + ((size_t)b * N_ + n0w + rloc) * H_;
        half8_t af[4];
#pragma unroll
        for (int kk = 0; kk < 4; ++kk) {
            const float4* p4 = (const float4*)(vrow + kk * 32 + colb);
            float4 f0 = p4[0], f1 = p4[1];
            half8_t a;
            a[0] = (_Float16)f0.x; a[1] = (_Float16)f0.y;
            a[2] = (_Float16)f0.z; a[3] = (_Float16)f0.w;
            a[4] = (_Float16)f1.x; a[5] = (_Float16)f1.y;
            a[6] = (_Float16)f1.z; a[7] = (_Float16)f1.w;
            af[kk] = a;
        }

        // ---- v_proj via MFMA + relu·wa partial logits
        float lp[4];
        lp[0] = lp[1] = lp[2] = lp[3] = 0.f;
#pragma unroll
        for (int pt = 0; pt < 8; ++pt) {
            const int p = pt * 16 + rloc;
            const float qv = qpcs[p];
            f32x4 acc = {qv, qv, qv, qv};      // C init = (q_proj+bq+bv)/sv
#pragma unroll
            for (int kk = 0; kk < 4; ++kk) {
                half8_t bf = *(const half8_t*)&Bl[(((kk * 8 + pt) * 64) + lane) * 8];
                acc = __builtin_amdgcn_mfma_f32_16x16x32_f16(af[kk], bf, acc, 0, 0, 0);
            }
            const float wv = was[p];           // wa*sa*sv: relu(sv x)=sv relu(x)
#pragma unroll
            for (int r = 0; r < 4; ++r)
                lp[r] += fmaxf(acc[r], 0.f) * wv;
        }
        // reduce over the 16 p-cols (lanes differing in bits 0-3)
#pragma unroll
        for (int m = 1; m <= 8; m <<= 1) {
#pragma unroll
            for (int r = 0; r < 4; ++r) lp[r] += __shfl_xor(lp[r], m, 64);
        }
        // lp[r] is now the logit of row (grp*4 + r); add bias + mask (LDS)
#pragma unroll
        for (int r = 0; r < 4; ++r) {
            const float mk = smask[r0 + grp * 4 + r];
            lp[r] += ba0 + (1.0f - mk) * (-10000.0f);
        }

        // transpose: lg_me = logit of row rloc (the row this lane HOLDS)
        const int srcl = (rloc >> 2) << 4;
        float t0 = __shfl(lp[0], srcl, 64);
        float t1 = __shfl(lp[1], srcl, 64);
        float t2 = __shfl(lp[2], srcl, 64);
        float t3 = __shfl(lp[3], srcl, 64);
        float a01 = (rloc & 1) ? t1 : t0;
        float a23 = (rloc & 1) ? t3 : t2;
        float lg_me = (rloc & 2) ? a23 : a01;

        // store logits (lanes 0..15 cover rows n0w..n0w+15, coalesced)
        if (lane < 16) ws[OFF_LOGITS + (size_t)b * N_ + n0w + lane] = lg_me;

        // wave max over its 16 rows
        float mt = fmaxf(fmaxf(lp[0], lp[1]), fmaxf(lp[2], lp[3]));
        mt = fmaxf(mt, __shfl_xor(mt, 16, 64));
        mt = fmaxf(mt, __shfl_xor(mt, 32, 64));

        // wave-private online softmax update
        const float mn = fmaxf(m_w, mt);
        const float alpha = __expf(m_w - mn);
        const float wme = __expf(lg_me - mn);
        float s = wme;
#pragma unroll
        for (int m = 1; m <= 8; m <<= 1) s += __shfl_xor(s, m, 64);
        l_w = l_w * alpha + s;
        m_w = mn;

        if (alpha != 1.0f) {
#pragma unroll
            for (int j = 0; j < 32; ++j) o32[j] *= alpha;
        }
        // o-update from the registers we already hold (f16 -> f32 cvt)
#pragma unroll
        for (int kk = 0; kk < 4; ++kk) {
#pragma unroll
            for (int j = 0; j < 8; ++j)
                o32[kk * 8 + j] += wme * (float)af[kk][j];
        }
    }

    // ---- intra-wave o reduction over the 16 rows (lanes, bits 0-3)
#pragma unroll
    for (int m = 1; m <= 8; m <<= 1) {
#pragma unroll
        for (int j = 0; j < 32; ++j) o32[j] += __shfl_xor(o32[j], m, 64);
    }
    {
        const int j0 = rloc * 2;
#pragma unroll
        for (int u = 0; u < 2; ++u) {
            const int j = j0 + u;
            obuf[w][(j >> 3) * 32 + colb + (j & 7)] = o32[j];
        }
        if (lane == 0) { mbuf[w] = m_w; lbuf[w] = l_w; }
    }
    __syncthreads();

    // ---- merge 4 wave partials -> chunk partial (no fences, no atomics)
    float* part = ws + OFF_PART + ((size_t)b * CCH + c) * 132;
    if (tid < P_) {
        const float mb = fmaxf(fmaxf(mbuf[0], mbuf[1]), fmaxf(mbuf[2], mbuf[3]));
        float lb = 0.f, oh = 0.f;
#pragma unroll
        for (int ww = 0; ww < 4; ++ww) {
            const float e = __expf(mbuf[ww] - mb);
            lb += e * lbuf[ww];
            oh += e * obuf[ww][tid];
        }
        part[2 + tid] = oh;
        if (tid == 0) { part[0] = mb; part[1] = lb; }
    }
}

// ---------- K2: combine chunk partials -> att; w = exp(logit-m)/l ----------
// Every thread redundantly recomputes (m,l) from the 8 chunk partials
// (16 broadcast loads + 8 exp — free); no barrier. grid (4, B):
// blockIdx.x = quarter of the N range; quarter 0 also writes att.
__global__ __launch_bounds__(256) void k2_final(
    const float* __restrict__ ws, float* __restrict__ out)
{
    const int c4 = blockIdx.x;          // 0..3, quarter of the row
    const int b  = blockIdx.y;
    const int tid = threadIdx.x;
    const float* part = ws + OFF_PART + (size_t)b * CCH * 132;

    float m = -1e30f;
#pragma unroll
    for (int cc = 0; cc < CCH; ++cc) m = fmaxf(m, part[cc * 132]);
    float l = 0.f;
#pragma unroll
    for (int cc = 0; cc < CCH; ++cc)
        l += __expf(part[cc * 132] - m) * part[cc * 132 + 1];
    const float il = 1.0f / l;

    if (c4 == 0 && tid < P_) {
        float a = 0.f;
#pragma unroll
        for (int cc = 0; cc < CCH; ++cc)
            a += __expf(part[cc * 132] - m) * part[cc * 132 + 2 + tid];
        out[(size_t)b * H_ + tid] = a * il;
    }

    const float4* lg4 = (const float4*)(ws + OFF_LOGITS + (size_t)b * N_ + c4 * 1024);
    float4* w4 = (float4*)(out + B_ * H_ + (size_t)b * N_ + c4 * 1024);
    float4 g = lg4[tid];
    float4 r;
    r.x = __expf(g.x - m) * il;
    r.y = __expf(g.y - m) * il;
    r.z = __expf(g.z - m) * il;
    r.w = __expf(g.w - m) * il;
    w4[tid] = r;
}

extern "C" void kernel_launch(void* const* d_in, const int* in_sizes, int n_in,
                              void* d_out, int out_size, void* d_ws, size_t ws_size,
                              hipStream_t stream) {
    const float* v    = (const float*)d_in[0];
    const float* q    = (const float*)d_in[1];
    const float* mask = (const float*)d_in[2];
    const float* Wv   = (const float*)d_in[3];
    const float* bv   = (const float*)d_in[4];
    const float* gv   = (const float*)d_in[5];
    const float* Wq   = (const float*)d_in[6];
    const float* bq   = (const float*)d_in[7];
    const float* gq   = (const float*)d_in[8];
    const float* Wa   = (const float*)d_in[9];
    const float* ba   = (const float*)d_in[10];
    const float* ga   = (const float*)d_in[11];
    float* out = (float*)d_out;
    float* ws  = (float*)d_ws;

    k1_main<<<dim3(CCH, B_), 256, 0, stream>>>(v, mask, ba, q, Wq, bq, bv,
                                               Wv, gv, gq, Wa, ga, ws);
    k2_final<<<dim3(4, B_), 256, 0, stream>>>(ws, out);
}